// Round 4
// baseline (114.018 us; speedup 1.0000x reference)
//
#include <hip/hip_runtime.h>

// RGate: apply Rx(angle[i]) to every qubit of a 22-qubit statevector.
// Gate on amp-bit k pairs indices at stride 2^k and uses angle[21-k].
// 3 passes, every pass: 32 KB LDS tile, 256 threads, >=4 blocks/CU, and all
// global segments >=256B aligned & block-exclusive (no half-line sharing —
// that was pass B's defect in the 2-pass round-3 version).
//   P1: bits 0-11, 4096-amp contiguous tile, float4 I/O, 2 re-tiles,
//       gates 8,9 via shfl_xor (m-bits 8,9 = lane bits 4,5).
//   P2: bits 12-16, tile 32H x 128l (l-chunk 512B), 1 re-tile.
//   P3: bits 17-21, same structure at stride 2^17.

constexpr int NTOT = 1 << 22;   // 2^22 amplitudes

__device__ __forceinline__ void rotg(float& ar, float& ai, float& br, float& bi,
                                     float c, float s) {
    // a' = c*a - i*s*b ; b' = c*b - i*s*a
    float t0 = ar, t1 = ai, t2 = br, t3 = bi;
    ar = fmaf(c, t0,  s * t3);
    ai = fmaf(c, t1, -s * t2);
    br = fmaf(c, t2,  s * t1);
    bi = fmaf(c, t3, -s * t0);
}

// NB butterfly gates for amp stride-bits K0..K0+NB-1, where amp bit (K0+b)
// lives at register-index bit (MSH+b). Angles are wave-uniform scalars.
template<int K0, int NB, int MSH>
__device__ __forceinline__ void gatesM(float (&ar)[16], float (&ai)[16],
                                       const float* __restrict__ ang) {
    #pragma unroll
    for (int b = 0; b < NB; ++b) {
        const int m = 1 << (MSH + b);
        const float a = 0.5f * ang[21 - (K0 + b)];
        const float c = cosf(a), s = sinf(a);
        #pragma unroll
        for (int j = 0; j < 16; ++j)
            if (!(j & m)) rotg(ar[j], ai[j], ar[j | m], ai[j | m], c, s);
    }
}

// Cross-lane gate: partner = lane ^ XOR (same wave). Symmetric update:
// x_r' = c*x_r + s*p_i ; x_i' = c*x_i - s*p_r  (holds for both pair members).
template<int XOR>
__device__ __forceinline__ void shflgate(float (&ar)[16], float (&ai)[16],
                                         float c, float s) {
    #pragma unroll
    for (int j = 0; j < 16; ++j) {
        float pr = __shfl_xor(ar[j], XOR, 64);
        float pi = __shfl_xor(ai[j], XOR, 64);
        ar[j] = fmaf(c, ar[j],  s * pi);
        ai[j] = fmaf(c, ai[j], -s * pr);
    }
}

// P1 LDS swizzle: fold idx bits 6-9 into bits 2-5 (involution, keeps bits 0,1
// so float4-group contiguity survives). Puts every arrangement at the b64/b128
// bank floor (lane-varying axes: W1 t-bits 4-7, R2 t-bits 2-5, R3 t-bits 4,5).
__device__ __forceinline__ int swz(int i) { return i ^ (((i >> 6) & 15) << 2); }

// ---------------- P1: bits 0..11, tile = 4096 contiguous -------------------
// 256 threads, 16 amps/thread, LDS 4096 float2 = 32 KB (4 blocks/CU).
// Arrangements (tile-local m):
//  L  (load):  m = (t<<2) + r + (q<<10)             -> reg {0,1 | 10,11}; gates 0,1,10,11
//  A2:         m = (t&3) + (j<<2) + ((t>>2)<<6)     -> reg = m bits 2-5;  gates 2-5
//  A3 (store): m = r + ((t&15)<<2) + (jj<<6) + ((t>>4)<<8)
//              -> reg {0,1 | 6,7}; gates 6,7; then gates 8,9 via shfl_xor(16/32)
__global__ __launch_bounds__(256, 4) void rgate_p1(const float* __restrict__ xr,
                                                   const float* __restrict__ xi,
                                                   const float* __restrict__ ang,
                                                   float* __restrict__ out) {
    __shared__ float2 sv[4096];          // 32 KB
    const int t  = threadIdx.x;
    const int g0 = blockIdx.x << 12;

    float ar[16], ai[16];
    #pragma unroll
    for (int q = 0; q < 4; ++q) {
        const int m = (t << 2) + (q << 10);
        float4 vr = *(const float4*)(xr + g0 + m);
        float4 vi = *(const float4*)(xi + g0 + m);
        ar[4*q+0] = vr.x; ar[4*q+1] = vr.y; ar[4*q+2] = vr.z; ar[4*q+3] = vr.w;
        ai[4*q+0] = vi.x; ai[4*q+1] = vi.y; ai[4*q+2] = vi.z; ai[4*q+3] = vi.w;
    }
    gatesM<0, 2, 0>(ar, ai, ang);        // gates 0,1  (reg bits 0,1 = r)
    gatesM<10, 2, 2>(ar, ai, ang);       // gates 10,11 (reg bits 2,3 = q)

    #pragma unroll
    for (int q = 0; q < 4; ++q) {
        const int m = swz((t << 2) + (q << 10));
        #pragma unroll
        for (int r = 0; r < 4; ++r)
            sv[m + r] = make_float2(ar[4*q+r], ai[4*q+r]);
    }
    __syncthreads();

    // A2: reg = m bits 2-5
    const int b2 = (t & 3) | ((t >> 2) << 6);
    #pragma unroll
    for (int j = 0; j < 16; ++j) {
        float2 v = sv[swz(b2 + (j << 2))];
        ar[j] = v.x; ai[j] = v.y;
    }
    gatesM<2, 4, 0>(ar, ai, ang);        // gates 2-5
    #pragma unroll
    for (int j = 0; j < 16; ++j)
        sv[swz(b2 + (j << 2))] = make_float2(ar[j], ai[j]);
    __syncthreads();

    // A3: reg = {m bits 0,1 | m bits 6,7}
    const int b3 = ((t & 15) << 2) | ((t >> 4) << 8);
    #pragma unroll
    for (int jj = 0; jj < 4; ++jj) {
        const int m = swz(b3 + (jj << 6));
        #pragma unroll
        for (int r = 0; r < 4; ++r) {
            float2 v = sv[m + r];
            ar[4*jj+r] = v.x; ai[4*jj+r] = v.y;
        }
    }
    gatesM<6, 2, 2>(ar, ai, ang);        // gates 6,7 (reg bits 2,3 = jj)
    {   // gates 8,9: m bit 8 = t bit 4, m bit 9 = t bit 5 -> in-wave shfl
        float a8 = 0.5f * ang[21 - 8], a9 = 0.5f * ang[21 - 9];
        shflgate<16>(ar, ai, cosf(a8), sinf(a8));
        shflgate<32>(ar, ai, cosf(a9), sinf(a9));
    }
    #pragma unroll
    for (int jj = 0; jj < 4; ++jj) {
        const int m = b3 + (jj << 6);
        *(float4*)(out + g0 + m)        = make_float4(ar[4*jj], ar[4*jj+1], ar[4*jj+2], ar[4*jj+3]);
        *(float4*)(out + NTOT + g0 + m) = make_float4(ai[4*jj], ai[4*jj+1], ai[4*jj+2], ai[4*jj+3]);
    }
}

// ---------------- P2/P3 shared structure -----------------------------------
// Tile = 32 H (strided) x 128 l (contiguous). 256 threads, 16 amps/thread:
// sub = t&63 -> l = 2*sub+p (float2), hw = t>>6 in [0,4).
//  arr1 (load):  H = j | (hw<<3), j in [0,8) -> reg bits 1-3 = H bits 0-2
//  arr2 (store): H = hw | (j<<2)             -> reg bits 2,3  = H bits 3,4
// Global: per wave-instr 64 lanes x float2, wave-uniform H -> 512 B contiguous,
// block-exclusive. LDS sv[H*128 + l] float2: byte = 1024H + 8l -> bank pattern
// independent of H -> conflict-free at floor. One re-tile, float4 LDS ops.
template<int KBASE, int HSH>
__device__ __forceinline__ void rgate_strided(const float* __restrict__ ang,
                                              float* __restrict__ out,
                                              int base) {
    __shared__ float2 sv[4096];          // 32 KB
    const int t   = threadIdx.x;
    const int sub = t & 63, hw = t >> 6;
    float* outr = out;
    float* outi = out + NTOT;

    float ar[16], ai[16];
    #pragma unroll
    for (int j = 0; j < 8; ++j) {
        const int g = base + ((j | (hw << 3)) << HSH);
        float2 vr = *(const float2*)(outr + g);
        float2 vi = *(const float2*)(outi + g);
        ar[2*j] = vr.x; ar[2*j+1] = vr.y;
        ai[2*j] = vi.x; ai[2*j+1] = vi.y;
    }
    gatesM<KBASE, 3, 1>(ar, ai, ang);    // gates KBASE..KBASE+2 (H bits 0-2)

    #pragma unroll
    for (int j = 0; j < 8; ++j) {
        const int idx = ((j | (hw << 3)) << 7) + 2 * sub;
        *(float4*)(&sv[idx]) = make_float4(ar[2*j], ai[2*j], ar[2*j+1], ai[2*j+1]);
    }
    __syncthreads();

    #pragma unroll
    for (int j = 0; j < 8; ++j) {
        const int idx = ((hw | (j << 2)) << 7) + 2 * sub;
        float4 v = *(const float4*)(&sv[idx]);
        ar[2*j] = v.x; ai[2*j] = v.y;
        ar[2*j+1] = v.z; ai[2*j+1] = v.w;
    }
    gatesM<KBASE + 3, 2, 2>(ar, ai, ang); // gates KBASE+3,KBASE+4 (H bits 3,4)

    #pragma unroll
    for (int j = 0; j < 8; ++j) {
        const int g = base + ((hw | (j << 2)) << HSH);
        *(float2*)(outr + g) = make_float2(ar[2*j], ar[2*j+1]);
        *(float2*)(outi + g) = make_float2(ai[2*j], ai[2*j+1]);
    }
}

// P2: bits 12-16. amp = u*2^17 + H*2^12 + c*128 + l; bid -> (u = bid>>5, c = bid&31)
__global__ __launch_bounds__(256, 4) void rgate_p2(const float* __restrict__ ang,
                                                   float* __restrict__ out) {
    const int u = blockIdx.x >> 5, c = blockIdx.x & 31;
    const int base = (u << 17) + (c << 7) + 2 * (threadIdx.x & 63);
    rgate_strided<12, 12>(ang, out, base);
}

// P3: bits 17-21. amp = H*2^17 + c*128 + l; c = bid in [0,1024)
__global__ __launch_bounds__(256, 4) void rgate_p3(const float* __restrict__ ang,
                                                   float* __restrict__ out) {
    const int base = (blockIdx.x << 7) + 2 * (threadIdx.x & 63);
    rgate_strided<17, 17>(ang, out, base);
}

extern "C" void kernel_launch(void* const* d_in, const int* in_sizes, int n_in,
                              void* d_out, int out_size, void* d_ws, size_t ws_size,
                              hipStream_t stream) {
    const float* xr  = (const float*)d_in[0];
    const float* xi  = (const float*)d_in[1];
    const float* ang = (const float*)d_in[2];
    float* out = (float*)d_out;

    // P1: bits 0-11, d_in -> d_out (fully overwrites d_out)
    rgate_p1<<<1024, 256, 0, stream>>>(xr, xi, ang, out);
    // P2: bits 12-16, in-place
    rgate_p2<<<1024, 256, 0, stream>>>(ang, out);
    // P3: bits 17-21, in-place
    rgate_p3<<<1024, 256, 0, stream>>>(ang, out);
}

// Round 5
// 106.608 us; speedup vs baseline: 1.0695x; 1.0695x over previous
//
#include <hip/hip_runtime.h>

// RGate: apply Rx(angle[i]) to every qubit of a 22-qubit statevector.
// Gate on amp-bit k pairs indices at stride 2^k and uses angle[21-k].
//
// STRUCTURE (best measured: 106.3 us; 2-pass = structural minimum):
//   Pass A: bits 0-12, contiguous 8192-amp tile (64 KB LDS), float4 I/O,
//           3 LDS re-tiles. 512 thr -> 2 blocks/CU so load/compute/store
//           phases overlap across blocks.
//   Pass B: bits 13-21, tile 512H x 16l (64 KB), 1 re-tile + shfl_xor for
//           bit 17. 64B global segments are absorbed by sectored L2
//           (measured: pass B ~= clean-geometry pass time).
// Session accounting: ~86 us fixed harness overhead (2 fills) + ~10 us/pass
// at the memory floor. 3-pass variants measured +8 us (R4); 128 KB tiles
// serialize phases at 1 blk/CU (+10 us, R2). Do not change pass count or
// tile size without re-deriving.

constexpr int NTOT = 1 << 22;   // 2^22 amplitudes

__device__ __forceinline__ void rotg(float& ar, float& ai, float& br, float& bi,
                                     float c, float s) {
    // a' = c*a - i*s*b ; b' = c*b - i*s*a
    float t0 = ar, t1 = ai, t2 = br, t3 = bi;
    ar = fmaf(c, t0,  s * t3);
    ai = fmaf(c, t1, -s * t2);
    br = fmaf(c, t2,  s * t1);
    bi = fmaf(c, t3, -s * t0);
}

// NB butterfly gates for amp stride-bits K0..K0+NB-1, where amp bit (K0+b)
// lives at register-index bit (MSH+b). Angles are wave-uniform scalars.
template<int K0, int NB, int MSH>
__device__ __forceinline__ void gatesM(float (&ar)[16], float (&ai)[16],
                                       const float* __restrict__ ang) {
    #pragma unroll
    for (int b = 0; b < NB; ++b) {
        const int m = 1 << (MSH + b);
        const float a = 0.5f * ang[21 - (K0 + b)];
        const float c = cosf(a), s = sinf(a);
        #pragma unroll
        for (int j = 0; j < 16; ++j)
            if (!(j & m)) rotg(ar[j], ai[j], ar[j | m], ai[j | m], c, s);
    }
}

// Pass-A LDS swizzle: fold index bits 4..7 into bank-pair bits 0..3.
// Self-inverse bijection on [0,8192). Verified b64 4-cycle floor for all
// four arrangements (lane strides 4, 1-contig, 64-contig, 4).
__device__ __forceinline__ int slotA(int i) { return i ^ ((i >> 4) & 15); }

// ---------------- Pass A: bits 0..12, tile = 8192 contiguous ---------------
// 512 threads, 16 amps/thread, LDS 8192 float2 = 64 KB (2 blocks/CU).
// Arrangements (tile-local index i, reg j):
//  A1 (load):  i = (t<<2) + r + (q<<11), j=r+4q -> reg bits {0,1,11,12};
//              gates 11,12 (float4 loads)
//  A2:         i = (t&3)  + (j<<2) + ((t>>2)<<6)  -> bits {2..5};  gates 2-5
//  A3:         i = (t&63) + (j<<6) + ((t>>6)<<10) -> bits {6..9};  gates 6-9
//  A4 (store): i = r + ((t&255)<<2) + (q<<10) + ((t>>8)<<12)
//              -> reg bits {0,1,10,11}; gates 0,1,10 (float4 stores)
__global__ __launch_bounds__(512, 4) void rgate_A(const float* __restrict__ xr,
                                                  const float* __restrict__ xi,
                                                  const float* __restrict__ ang,
                                                  float* __restrict__ out) {
    __shared__ float2 sv[8192];          // 64 KB
    const int t  = threadIdx.x;
    const int g0 = blockIdx.x << 13;

    float ar[16], ai[16];
    #pragma unroll
    for (int q = 0; q < 4; ++q) {
        const int i = (t << 2) + (q << 11);
        float4 vr = *(const float4*)(xr + g0 + i);
        float4 vi = *(const float4*)(xi + g0 + i);
        ar[4*q+0] = vr.x; ar[4*q+1] = vr.y; ar[4*q+2] = vr.z; ar[4*q+3] = vr.w;
        ai[4*q+0] = vi.x; ai[4*q+1] = vi.y; ai[4*q+2] = vi.z; ai[4*q+3] = vi.w;
    }
    gatesM<11, 2, 2>(ar, ai, ang);       // gates 11,12 on reg bits 2,3 (=q)

    #pragma unroll
    for (int q = 0; q < 4; ++q)
        #pragma unroll
        for (int r = 0; r < 4; ++r)
            sv[slotA((t << 2) + r + (q << 11))] = make_float2(ar[4*q+r], ai[4*q+r]);
    __syncthreads();

    // A2: reg bits {2..5}
    const int b2 = (t & 3) + ((t >> 2) << 6);
    #pragma unroll
    for (int j = 0; j < 16; ++j) {
        float2 v = sv[slotA(b2 + (j << 2))];
        ar[j] = v.x; ai[j] = v.y;
    }
    gatesM<2, 4, 0>(ar, ai, ang);
    #pragma unroll
    for (int j = 0; j < 16; ++j)
        sv[slotA(b2 + (j << 2))] = make_float2(ar[j], ai[j]);
    __syncthreads();

    // A3: reg bits {6..9}
    const int b3 = (t & 63) + ((t >> 6) << 10);
    #pragma unroll
    for (int j = 0; j < 16; ++j) {
        float2 v = sv[slotA(b3 + (j << 6))];
        ar[j] = v.x; ai[j] = v.y;
    }
    gatesM<6, 4, 0>(ar, ai, ang);
    #pragma unroll
    for (int j = 0; j < 16; ++j)
        sv[slotA(b3 + (j << 6))] = make_float2(ar[j], ai[j]);
    __syncthreads();

    // A4: reg bits {0,1,10,11} -> gates 0,1 (reg bits 0,1) + gate 10 (reg bit 2)
    const int b4 = ((t & 255) << 2) + ((t >> 8) << 12);
    #pragma unroll
    for (int q = 0; q < 4; ++q)
        #pragma unroll
        for (int r = 0; r < 4; ++r) {
            float2 v = sv[slotA(b4 + r + (q << 10))];
            ar[4*q+r] = v.x; ai[4*q+r] = v.y;
        }
    gatesM<0, 2, 0>(ar, ai, ang);        // gates 0,1
    gatesM<10, 1, 2>(ar, ai, ang);       // gate 10 on reg bit 2 (=q)

    #pragma unroll
    for (int q = 0; q < 4; ++q) {
        const int i = b4 + (q << 10);
        *(float4*)(out + g0 + i)        = make_float4(ar[4*q], ar[4*q+1], ar[4*q+2], ar[4*q+3]);
        *(float4*)(out + NTOT + g0 + i) = make_float4(ai[4*q], ai[4*q+1], ai[4*q+2], ai[4*q+3]);
    }
}

// ---------------- Pass B: bits 13..21 (h stride 8192) ----------------------
// amp = h*8192 + l, h in [0,512) (h bit k = amp bit 13+k); tile = all h x
// 16 contiguous l = 8192 amps = 64 KB. 512 threads, 16 amps/thread.
// sub = t&15 (l), hw = t>>4 in [0,32).
//  B1 (load):  h = j | (hw<<4) -> reg = h bits 0..3 -> gates 13-16;
//              then gate 17 (h bit 4 = lane bit 4) via __shfl_xor(.,16)
//  B2 (store): h = hw | (j<<5) -> reg = h bits 5..8 -> gates 18-21
// LDS layout sv[h*16+sub]: both arrangements conflict-free (b64 floor).
// XCD remap: round-robin dispatch puts bid and bid+8 on the same XCD;
// remap makes those two blocks own adjacent 64B l-chunks (shared 128B line).
__global__ __launch_bounds__(512, 4) void rgate_B(const float* __restrict__ ang,
                                                  float* __restrict__ out) {
    __shared__ float2 sv[8192];          // 64 KB
    const int t   = threadIdx.x;
    const int bid = blockIdx.x;
    const int blk = (bid >> 3) | ((bid & 7) << 6);   // XCD-contiguous remap
    const int sub = t & 15, hw = t >> 4;
    const int lbase = (blk << 4) + sub;
    float* outr = out;
    float* outi = out + NTOT;

    float ar[16], ai[16];
    #pragma unroll
    for (int j = 0; j < 16; ++j) {
        const int g = ((j | (hw << 4)) << 13) + lbase;
        ar[j] = outr[g]; ai[j] = outi[g];
    }
    gatesM<13, 4, 0>(ar, ai, ang);       // gates 13-16

    {   // gate 17: partner = lane^16 (same wave). Symmetric update:
        // x_r' = c*x_r + s*p_i ; x_i' = c*x_i - s*p_r  (p = partner amp)
        const float a = 0.5f * ang[21 - 17];
        const float c = cosf(a), s = sinf(a);
        #pragma unroll
        for (int j = 0; j < 16; ++j) {
            float pr = __shfl_xor(ar[j], 16, 64);
            float pi = __shfl_xor(ai[j], 16, 64);
            ar[j] = fmaf(c, ar[j],  s * pi);
            ai[j] = fmaf(c, ai[j], -s * pr);
        }
    }

    #pragma unroll
    for (int j = 0; j < 16; ++j)
        sv[((j | (hw << 4)) << 4) + sub] = make_float2(ar[j], ai[j]);
    __syncthreads();

    #pragma unroll
    for (int j = 0; j < 16; ++j) {
        float2 v = sv[((hw | (j << 5)) << 4) + sub];
        ar[j] = v.x; ai[j] = v.y;
    }
    gatesM<18, 4, 0>(ar, ai, ang);       // gates 18-21

    #pragma unroll
    for (int j = 0; j < 16; ++j) {
        const int g = ((hw | (j << 5)) << 13) + lbase;
        outr[g] = ar[j]; outi[g] = ai[j];
    }
}

extern "C" void kernel_launch(void* const* d_in, const int* in_sizes, int n_in,
                              void* d_out, int out_size, void* d_ws, size_t ws_size,
                              hipStream_t stream) {
    const float* xr  = (const float*)d_in[0];
    const float* xi  = (const float*)d_in[1];
    const float* ang = (const float*)d_in[2];
    float* out = (float*)d_out;

    // Pass A: bits 0-12, d_in -> d_out (fully overwrites d_out)
    rgate_A<<<512, 512, 0, stream>>>(xr, xi, ang, out);
    // Pass B: bits 13-21, in-place on d_out
    rgate_B<<<512, 512, 0, stream>>>(ang, out);
}